// Round 15
// baseline (736.548 us; speedup 1.0000x reference)
//
#include <hip/hip_runtime.h>

typedef _Float16 F16;
typedef __attribute__((ext_vector_type(8))) _Float16 f16x8;
typedef __attribute__((ext_vector_type(4))) _Float16 f16x4;
typedef __attribute__((ext_vector_type(4))) float f32x4;

constexpr int NTOK = 8192;   // B*T
constexpr int C    = 1024;   // d_model
constexpr int FF   = 2048;   // d_ff
constexpr int NE   = 8;      // experts
constexpr int NRT  = 72;     // max routed 256-row tiles: 16384/256 + 8
constexpr int NST  = 32;     // shared-expert tiles: 8192/256
constexpr int MAXT = NRT + NST;     // 104
constexpr int SBASE = NRT * 256;    // shared rows start here in H/Y
constexpr int ROWS = SBASE + NTOK;  // 26624

constexpr int NBWGU = 18 * 128;     // gate/up: 16 kt * 8 nt per z
constexpr int NBWD  = 9 * 128;      // w_down: 32 kt * 4 nt per z
constexpr int NBRT  = NTOK / 4;     // router blocks

// ---- tiled layouts ----
// WGU: per e: [C/64 kt][2FF n'][64]   (n' = gate/up 16-col interleave)
// WD : per z: [FF/64 kt][C n][64]
// H  : [16 ct][ROWS][128]   (ct = ffcol/128)
// Y  : [4 ct][ROWS][256]    (ct = col/256)

#define MI_CNT 0
#define MI_CUR 8
#define MI_BASE 16
#define MI_TE 32
#define MI_TR (32 + MAXT)

__device__ __forceinline__ void gload16(const void* g, void* l) {
  __builtin_amdgcn_global_load_lds(
      (__attribute__((address_space(1))) void*)g,
      (__attribute__((address_space(3))) void*)l, 16, 0, 0);
}
#define VMCNT4() asm volatile("s_waitcnt vmcnt(4)" ::: "memory")
#define VMCNT0() asm volatile("s_waitcnt vmcnt(0)" ::: "memory")
#define BARR()   __builtin_amdgcn_s_barrier()
#define PRIO1()  __builtin_amdgcn_s_setprio(1)
#define PRIO0()  __builtin_amdgcn_s_setprio(0)

// ======= weight transpose+cast v3: all-coalesced via LDS bounce =============
// Reads: 1KB-contiguous float4 bursts (row-major fp32). Convert in reg.
// LDS f16 [64][258] (pad 2 -> row-parity bank split: writes conflict-free).
// Stores: 1KB wave bursts (8 rows x 128B per instr), R14-proven mapping.
__global__ __launch_bounds__(256) void k_tw(
    const float* __restrict__ wgate, const float* __restrict__ sg,
    const float* __restrict__ wup, const float* __restrict__ su,
    const float* __restrict__ wdown, const float* __restrict__ sd,
    F16* __restrict__ WGU, F16* __restrict__ WD) {
  __shared__ F16 tl[64 * 258];   // 33 KB
  const int id = blockIdx.x, tid = threadIdx.x;
  int nt, kt, N, sel = 0;
  bool il;
  const float* src;
  F16* dchunk;   // base of the [n][64] chunk this block writes into
  if (id < NBWGU) {
    const int z = id >> 7, rem = id & 127;
    nt = rem & 7; kt = rem >> 3;           // N=2048: 8 nt; K=1024: 16 kt
    N = FF; il = true; sel = z & 1;
    const int e = z >> 1;
    src = sel ? ((e < NE) ? wup + (size_t)e * C * FF : su)
              : ((e < NE) ? wgate + (size_t)e * C * FF : sg);
    dchunk = WGU + (size_t)e * 2 * FF * C + (size_t)kt * (2 * FF * 64);
  } else {
    const int id2 = id - NBWGU;
    const int z = id2 >> 7, rem = id2 & 127;
    nt = rem & 3; kt = rem >> 2;           // N=1024: 4 nt; K=2048: 32 kt
    N = C; il = false;
    src = (z < NE) ? wdown + (size_t)z * FF * C : sd;
    dchunk = WD + (size_t)z * C * FF + (size_t)kt * (C * 64);
  }
  const int n0 = nt * 256, k0 = kt * 64;

  // load 64k x 256n fp32 tile: 16 float4 per thread, 1KB per wave-instr
#pragma unroll
  for (int u = 0; u < 16; ++u) {
    const int flat = u * 256 + tid;        // float4 index in tile
    const int row = flat >> 6;             // k-local
    const int c4 = (flat & 63) * 4;        // n-local
    const float4 v = *(const float4*)&src[(size_t)(k0 + row) * N + n0 + c4];
    f16x4 h;
    h[0] = (F16)v.x; h[1] = (F16)v.y; h[2] = (F16)v.z; h[3] = (F16)v.w;
    *(f16x4*)&tl[row * 258 + c4] = h;
  }
  __syncthreads();

  // store: 8 f16x8 per thread; instr j: lanes cover 8 out-rows x 128B = 1KB
#pragma unroll
  for (int j = 0; j < 8; ++j) {
    const int flat = j * 256 + tid;        // f16x8 chunk index (2048 total)
    const int nl = flat >> 3;              // n-local 0..255
    const int o = flat & 7;                // k-chunk
    f16x8 ov;
#pragma unroll
    for (int u = 0; u < 8; ++u) ov[u] = tl[(o * 8 + u) * 258 + nl];
    const int n = n0 + nl;
    const int row = il ? (((n >> 4) << 5) | (sel << 4) | (n & 15)) : n;
    *(f16x8*)&dchunk[(size_t)row * 64 + o * 8] = ov;
  }
}

// ======= router (+fused x cast): fp64 logits, top-2, softmax ================
__global__ __launch_bounds__(256) void k_router(
    const float* __restrict__ x, const float* __restrict__ rw,
    F16* __restrict__ xh, int* __restrict__ meta,
    int* __restrict__ te0, int* __restrict__ te1,
    float* __restrict__ tw0, float* __restrict__ tw1) {
  __shared__ float lrw[NE * C];
  const int tid = threadIdx.x;
  for (int i = tid; i < NE * C / 4; i += 256)
    ((float4*)lrw)[i] = ((const float4*)rw)[i];
  __syncthreads();
  const int lane = tid & 63, wid = tid >> 6;
  const int tok = blockIdx.x * 4 + wid;
  const float* xr = x + (size_t)tok * C;
  float xv[16];
#pragma unroll
  for (int i = 0; i < 4; i++) {
    float4 v = ((const float4*)xr)[lane * 4 + i];
    xv[i * 4 + 0] = v.x; xv[i * 4 + 1] = v.y; xv[i * 4 + 2] = v.z; xv[i * 4 + 3] = v.w;
  }
#pragma unroll
  for (int i = 0; i < 4; i++) {
    f16x4 o;
    o.x = (F16)xv[i * 4 + 0]; o.y = (F16)xv[i * 4 + 1];
    o.z = (F16)xv[i * 4 + 2]; o.w = (F16)xv[i * 4 + 3];
    ((f16x4*)(xh + (size_t)tok * C))[lane * 4 + i] = o;
  }
  double lg[NE];
#pragma unroll
  for (int e = 0; e < NE; e++) {
    double s = 0.0;
#pragma unroll
    for (int i = 0; i < 16; i++)
      s += (double)xv[i] * (double)lrw[e * C + lane * 16 + i];
#pragma unroll
    for (int d = 1; d < 64; d <<= 1) s += __shfl_xor(s, d, 64);
    lg[e] = s;
  }
  double b0 = -1e300; int i0 = 0;
#pragma unroll
  for (int e = 0; e < NE; e++) if (lg[e] > b0) { b0 = lg[e]; i0 = e; }
  double b1 = -1e300; int i1 = 0;
#pragma unroll
  for (int e = 0; e < NE; e++) if (e != i0 && lg[e] > b1) { b1 = lg[e]; i1 = e; }
  const float ex = __expf((float)(b1 - b0));
  const float w0 = 1.f / (1.f + ex), w1 = ex / (1.f + ex);
  if (lane == 0) {
    te0[tok] = i0; te1[tok] = i1; tw0[tok] = w0; tw1[tok] = w1;
    atomicAdd(&meta[MI_CNT + i0], 1);
    atomicAdd(&meta[MI_CNT + i1], 1);
  }
}

// ---------------- scan: bases, tile map (routed + shared), pad fill ----------
__global__ __launch_bounds__(256) void k_scan(int* __restrict__ meta,
                                              int* __restrict__ rowtok) {
  __shared__ int s_cnt[NE], s_base[NE];
  if (threadIdx.x == 0) {
    int b = 0, nt = 0;
    for (int e = 0; e < NE; e++) {
      int c = meta[MI_CNT + e];
      s_cnt[e] = c; s_base[e] = b;
      meta[MI_BASE + e] = b;
      meta[MI_CUR + e] = 0;
      int tiles = (c + 255) >> 8;
      for (int t = 0; t < tiles; t++) {
        meta[MI_TE + nt] = e;
        meta[MI_TR + nt] = b + t * 256;
        nt++;
      }
      b += tiles << 8;
    }
    for (int t = nt; t < NRT; t++) meta[MI_TE + t] = -1;
    for (int t = 0; t < NST; t++) {
      meta[MI_TE + NRT + t] = NE;
      meta[MI_TR + NRT + t] = SBASE + t * 256;
    }
  }
  __syncthreads();
  for (int e = 0; e < NE; e++) {
    int c = s_cnt[e], b = s_base[e];
    int al = (c + 255) & ~255;
    for (int i = c + threadIdx.x; i < al; i += 256) rowtok[b + i] = -1;
  }
}

// ---------------- scatter tokens into expert buckets (+slot record) ---------
__global__ __launch_bounds__(256) void k_scatter(const int* __restrict__ te0,
                                                 const int* __restrict__ te1,
                                                 int* __restrict__ meta,
                                                 int* __restrict__ rowtok,
                                                 int* __restrict__ sl0,
                                                 int* __restrict__ sl1) {
  int t = blockIdx.x * 256 + threadIdx.x;
  int e0 = te0[t], e1 = te1[t];
  int p0 = atomicAdd(&meta[MI_CUR + e0], 1);
  int r0 = meta[MI_BASE + e0] + p0;
  rowtok[r0] = t; sl0[t] = r0;
  int p1 = atomicAdd(&meta[MI_CUR + e1], 1);
  int r1 = meta[MI_BASE + e1] + p1;
  rowtok[r1] = t; sl1[t] = r1;
}

// ============ MFMA / ds_read helpers ============
__device__ __forceinline__ void read_a(f16x8 (&ar)[2][2], const F16* sAc,
                                       const int* aoff, int m0) {
  ar[0][0] = *(const f16x8*)&sAc[aoff[m0]];
  ar[0][1] = *(const f16x8*)&sAc[aoff[m0] ^ 32];
  ar[1][0] = *(const f16x8*)&sAc[aoff[m0 + 1]];
  ar[1][1] = *(const f16x8*)&sAc[aoff[m0 + 1] ^ 32];
}
__device__ __forceinline__ void mfma_pair(f32x4 (&a0)[4], f32x4 (&a1)[4],
                                          const f16x8 (&ar)[2][2],
                                          const f16x8 (&bb)[4][2]) {
#pragma unroll
  for (int ni = 0; ni < 4; ++ni) {
    a0[ni] = __builtin_amdgcn_mfma_f32_16x16x32_f16(ar[0][0], bb[ni][0], a0[ni], 0, 0, 0);
    a1[ni] = __builtin_amdgcn_mfma_f32_16x16x32_f16(ar[1][0], bb[ni][0], a1[ni], 0, 0, 0);
  }
#pragma unroll
  for (int ni = 0; ni < 4; ++ni) {
    a0[ni] = __builtin_amdgcn_mfma_f32_16x16x32_f16(ar[0][1], bb[ni][1], a0[ni], 0, 0, 0);
    a1[ni] = __builtin_amdgcn_mfma_f32_16x16x32_f16(ar[1][1], bb[ni][1], a1[ni], 0, 0, 0);
  }
}

// ======= unified 256x256 grouped GEMM — R14 frame, n-block offset param =====
// blockIdx.x = y-tile (fast), n-block = blockIdx.y + NB0 (gemm1 split into
// two dispatches for profiling visibility). K-loop identical to R14.
template <bool G1, int NB0>
__global__ __launch_bounds__(512, 2) void k_gemm(const F16* __restrict__ Asrc,
                                                 const F16* __restrict__ Wsrc,
                                                 F16* __restrict__ Dst,
                                                 const int* __restrict__ meta,
                                                 const int* __restrict__ rowtok) {
  constexpr int K = G1 ? C : FF;
  constexpr int NT = K / 64;
  constexpr int TILE = 256 * 64;
  constexpr size_t BCH = (size_t)(G1 ? 2 * FF : C) * 64;   // B chunk stride
  const int e = meta[MI_TE + blockIdx.x];
  if (e < 0) return;
  const int row0 = meta[MI_TR + blockIdx.x];
  const int nb = blockIdx.y + NB0;
  const int n0 = nb * 256;
  const F16* WB = Wsrc + (size_t)e * (size_t)(G1 ? 2 * FF : C) * K;
  __shared__ __align__(16) F16 smem[4 * TILE];   // 128 KB: A0,A1,B0,B1
  const int tid = threadIdx.x, lane = tid & 63, wid = tid >> 6;
  const int wm = wid >> 2, wn = wid & 3;

  const int srow = tid >> 3;
  const int scol = ((tid & 7) ^ (srow & 7)) << 3;
  const F16 *pa0[4], *pb0[4];
#pragma unroll
  for (int i = 0; i < 4; ++i) {
    const int r = i * 64 + srow;
    int arow;
    if (G1) {
      int tok = (e == NE) ? (row0 - SBASE + r) : rowtok[row0 + r];
      if (tok < 0) tok = 0;   // pad row: harmless dup, never combined
      arow = tok;
    } else {
      arow = row0 + r;
    }
    pa0[i] = G1 ? (Asrc + (size_t)arow * C + scol)
                : (Asrc + (size_t)arow * 128 + scol);    // H tiled [ct][row][128]
    pb0[i] = WB + (size_t)(n0 + i * 64 + srow) * 64 + scol;  // chunk-tiled
  }
  const int ldsrow = wid * 8;
  auto a_off = [&](int t1) -> size_t {
    return G1 ? (size_t)t1 * 64
              : (size_t)(t1 >> 1) * ((size_t)ROWS * 128) + (size_t)(t1 & 1) * 64;
  };

  const int fro = lane & 15, q = lane >> 4;
  int aoff[8], boff[4];
#pragma unroll
  for (int f = 0; f < 8; ++f) {
    const int r = wm * 128 + f * 16 + fro;
    aoff[f] = r * 64 + ((q ^ (r & 7)) << 3);
  }
#pragma unroll
  for (int ni = 0; ni < 4; ++ni) {
    const int r = wn * 64 + ni * 16 + fro;
    boff[ni] = r * 64 + ((q ^ (r & 7)) << 3);
  }

  f32x4 acc[8][4];
  const f32x4 fz = {0.f, 0.f, 0.f, 0.f};
#pragma unroll
  for (int i = 0; i < 8; ++i)
#pragma unroll
    for (int j = 0; j < 4; ++j) acc[i][j] = fz;

  // prologue: stage tile 0 (A -> smem[0], B -> smem[2*TILE])
#pragma unroll
  for (int i = 0; i < 4; ++i) {
    gload16(pa0[i], &smem[(i * 64 + ldsrow) * 64]);
    gload16(pb0[i], &smem[2 * TILE + (i * 64 + ldsrow) * 64]);
  }

  for (int t = 0; t < NT; ++t) {
    const int cur = t & 1, nxt = cur ^ 1;
    const F16* sAc = smem + cur * TILE;
    const F16* sBc = smem + (2 + cur) * TILE;
    F16* sAn = smem + nxt * TILE;
    F16* sBn = smem + (2 + nxt) * TILE;
    const bool st = (t + 1 < NT);
    const size_t ag = a_off(t + 1);
    const size_t bg = (size_t)(t + 1) * BCH;

    if (st) {
#pragma unroll
      for (int i = 0; i < 4; ++i)
        gload16(pa0[i] + ag, &sAn[(i * 64 + ldsrow) * 64]);
      VMCNT4();
    } else {
      VMCNT0();
    }
    BARR();

    f16x8 bb[4][2], ar[2][2];
#pragma unroll
    for (int ni = 0; ni < 4; ++ni) {
      bb[ni][0] = *(const f16x8*)&sBc[boff[ni]];
      bb[ni][1] = *(const f16x8*)&sBc[boff[ni] ^ 32];
    }

    read_a(ar, sAc, aoff, 0);
    PRIO1(); mfma_pair(acc[0], acc[1], ar, bb); PRIO0();
    if (st) {
      gload16(pb0[0] + bg, &sBn[ldsrow * 64]);
      gload16(pb0[1] + bg, &sBn[(64 + ldsrow) * 64]);
    }
    read_a(ar, sAc, aoff, 2);
    PRIO1(); mfma_pair(acc[2], acc[3], ar, bb); PRIO0();
    if (st) {
      gload16(pb0[2] + bg, &sBn[(128 + ldsrow) * 64]);
      gload16(pb0[3] + bg, &sBn[(192 + ldsrow) * 64]);
    }
    read_a(ar, sAc, aoff, 4);
    PRIO1(); mfma_pair(acc[4], acc[5], ar, bb); PRIO0();
    read_a(ar, sAc, aoff, 6);
    PRIO1(); mfma_pair(acc[6], acc[7], ar, bb); PRIO0();

    if (st) BARR();
  }

  // ===== packed epilogue =====
  const int erow = q << 2, ecol = fro;
  BARR();   // all waves done reading smem K-tiles before overwrite
  if (G1) {
    F16* ep = smem;
#pragma unroll
    for (int mi = 0; mi < 8; ++mi)
#pragma unroll
      for (int pp = 0; pp < 2; ++pp)
#pragma unroll
        for (int j = 0; j < 4; ++j) {
          const int rl = wm * 128 + mi * 16 + erow + j;
          const float gv = acc[mi][2 * pp][j], uv = acc[mi][2 * pp + 1][j];
          const float h = gv / (1.f + __expf(-gv)) * uv;
          ep[rl * 136 + wn * 32 + pp * 16 + ecol] = (F16)h;
        }
    BARR();
    F16* Hc = Dst + (size_t)nb * ((size_t)ROWS * 128);
#pragma unroll
    for (int i = 0; i < 16; ++i) {
      const int flat = i * 512 + tid;
      const int row = flat >> 5, col4 = flat & 31;
      const f16x4 v = *(const f16x4*)&ep[row * 136 + col4 * 4];
      *(f16x4*)&Hc[(size_t)(row0 + row) * 128 + col4 * 4] = v;
    }
  } else {
    F16* ep = smem;
    F16* Yc = Dst + (size_t)nb * ((size_t)ROWS * 256);
#pragma unroll
    for (int h = 0; h < 2; ++h) {
      if (wm == h) {
#pragma unroll
        for (int mi = 0; mi < 8; ++mi)
#pragma unroll
          for (int ni = 0; ni < 4; ++ni)
#pragma unroll
            for (int j = 0; j < 4; ++j) {
              const int rl = mi * 16 + erow + j;
              ep[rl * 264 + wn * 64 + ni * 16 + ecol] = (F16)acc[mi][ni][j];
            }
      }
      BARR();
#pragma unroll
      for (int i = 0; i < 16; ++i) {
        const int flat = i * 512 + tid;
        const int row = flat >> 6, col4 = flat & 63;
        const f16x4 v = *(const f16x4*)&ep[row * 264 + col4 * 4];
        *(f16x4*)&Yc[(size_t)(row0 + h * 128 + row) * 256 + col4 * 4] = v;
      }
      if (h == 0) BARR();
    }
  }
}

// ---------------- combine: out = w0*Y[r0] + w1*Y[r1] + Y[shared] ------------
__global__ __launch_bounds__(256) void k_combine(const F16* __restrict__ Y,
                                                 const int* __restrict__ sl0,
                                                 const int* __restrict__ sl1,
                                                 const float* __restrict__ tw0,
                                                 const float* __restrict__ tw1,
                                                 float* __restrict__ out) {
  int idx = blockIdx.x * 256 + threadIdx.x;
  int t = idx >> 7, cg = idx & 127;
  int r0 = sl0[t], r1 = sl1[t];
  float w0 = tw0[t], w1 = tw1[t];
  const F16* Yc = Y + (size_t)(cg >> 5) * ((size_t)ROWS * 256);
  const int cin = (cg & 31) * 8;
  f16x8 y0 = *(const f16x8*)&Yc[(size_t)r0 * 256 + cin];
  f16x8 y1 = *(const f16x8*)&Yc[(size_t)r1 * 256 + cin];
  f16x8 ys = *(const f16x8*)&Yc[(size_t)(SBASE + t) * 256 + cin];
  float o[8];
#pragma unroll
  for (int j = 0; j < 8; j++)
    o[j] = w0 * (float)y0[j] + w1 * (float)y1[j] + (float)ys[j];
  float* op = out + (size_t)t * C + cg * 8;
  ((float4*)op)[0] = make_float4(o[0], o[1], o[2], o[3]);
  ((float4*)op)[1] = make_float4(o[4], o[5], o[6], o[7]);
}

// ---------------- host launch ----------------
extern "C" void kernel_launch(void* const* d_in, const int* in_sizes, int n_in,
                              void* d_out, int out_size, void* d_ws, size_t ws_size,
                              hipStream_t stream) {
  const float* x  = (const float*)d_in[0];
  const float* rw = (const float*)d_in[1];
  const float* wgate = (const float*)d_in[2];
  const float* wup   = (const float*)d_in[3];
  const float* wdown = (const float*)d_in[4];
  const float* sg = (const float*)d_in[5];
  const float* su = (const float*)d_in[6];
  const float* sd = (const float*)d_in[7];
  float* out = (float*)d_out;

  char* ws = (char*)d_ws;
  size_t o = 0;
  auto alloc = [&](size_t bytes) -> void* {
    void* p = ws + o;
    o += (bytes + 255) & ~(size_t)255;
    return p;
  };
  F16* xh  = (F16*)alloc((size_t)NTOK * C * 2);
  F16* WGU = (F16*)alloc((size_t)9 * 2 * FF * C * 2);
  F16* WD  = (F16*)alloc((size_t)9 * C * FF * 2);
  F16* Hb  = (F16*)alloc((size_t)ROWS * FF * 2);
  int* rowtok = (int*)alloc((size_t)SBASE * 4);
  int* meta = (int*)alloc(2048);
  int* te0 = (int*)alloc((size_t)NTOK * 4);
  int* te1 = (int*)alloc((size_t)NTOK * 4);
  float* tw0 = (float*)alloc((size_t)NTOK * 4);
  float* tw1 = (float*)alloc((size_t)NTOK * 4);
  int* sl0 = (int*)alloc((size_t)NTOK * 4);
  int* sl1 = (int*)alloc((size_t)NTOK * 4);
  if (o > ws_size) return;
  F16* Yb = WGU;   // overlay: WGU dead after gemm1; Y (54.5MB) < WGU (75.5MB)

  (void)hipMemsetAsync(meta, 0, 1024, stream);
  k_tw<<<NBWGU + NBWD, 256, 0, stream>>>(wgate, sg, wup, su, wdown, sd, WGU, WD);
  k_router<<<NBRT, 256, 0, stream>>>(x, rw, xh, meta, te0, te1, tw0, tw1);
  k_scan<<<1, 256, 0, stream>>>(meta, rowtok);
  k_scatter<<<NTOK / 256, 256, 0, stream>>>(te0, te1, meta, rowtok, sl0, sl1);
  k_gemm<true, 0><<<dim3(MAXT, 8), 512, 0, stream>>>(xh, WGU, Hb, meta, rowtok);
  k_gemm<true, 8><<<dim3(MAXT, 8), 512, 0, stream>>>(xh, WGU, Hb, meta, rowtok);
  k_gemm<false, 0><<<dim3(MAXT, C / 256), 512, 0, stream>>>(Hb, WD, Yb, meta, rowtok);
  k_combine<<<NTOK * (C / 8) / 256, 256, 0, stream>>>(Yb, sl0, sl1, tw0, tw1, out);
}

// Round 16
// 701.609 us; speedup vs baseline: 1.0498x; 1.0498x over previous
//
#include <hip/hip_runtime.h>

typedef _Float16 F16;
typedef __attribute__((ext_vector_type(8))) _Float16 f16x8;
typedef __attribute__((ext_vector_type(4))) _Float16 f16x4;
typedef __attribute__((ext_vector_type(4))) float f32x4;

constexpr int NTOK = 8192;   // B*T
constexpr int C    = 1024;   // d_model
constexpr int FF   = 2048;   // d_ff
constexpr int NE   = 8;      // experts
constexpr int NRT  = 72;     // max routed 256-row tiles: 16384/256 + 8
constexpr int NST  = 32;     // shared-expert tiles: 8192/256
constexpr int MAXT = NRT + NST;     // 104
constexpr int SBASE = NRT * 256;    // shared rows start here in H/Y
constexpr int ROWS = SBASE + NTOK;  // 26624

constexpr int NBWGU = 18 * 128;     // gate/up: 16 kt * 8 nt per z
constexpr int NBWD  = 9 * 128;      // w_down: 32 kt * 4 nt per z
constexpr int NBRT  = NTOK / 4;     // router blocks

// ---- tiled layouts ----
// WGU: per e: [C/64 kt][2FF n'][64]   (n' = gate/up 16-col interleave)
// WD : per z: [FF/64 kt][C n][64]
// H  : [16 ct][ROWS][128]   (ct = ffcol/128)
// Y  : [4 ct][ROWS][256]    (ct = col/256)

#define MI_CNT 0
#define MI_CUR 8
#define MI_BASE 16
#define MI_TE 32
#define MI_TR (32 + MAXT)

__device__ __forceinline__ void gload16(const void* g, void* l) {
  __builtin_amdgcn_global_load_lds(
      (__attribute__((address_space(1))) void*)g,
      (__attribute__((address_space(3))) void*)l, 16, 0, 0);
}
#define VMCNT4() asm volatile("s_waitcnt vmcnt(4)" ::: "memory")
#define VMCNT0() asm volatile("s_waitcnt vmcnt(0)" ::: "memory")
#define BARR()   __builtin_amdgcn_s_barrier()
#define PRIO1()  __builtin_amdgcn_s_setprio(1)
#define PRIO0()  __builtin_amdgcn_s_setprio(0)

// ======= weight transpose+cast v3: all-coalesced via LDS bounce =============
__global__ __launch_bounds__(256) void k_tw(
    const float* __restrict__ wgate, const float* __restrict__ sg,
    const float* __restrict__ wup, const float* __restrict__ su,
    const float* __restrict__ wdown, const float* __restrict__ sd,
    F16* __restrict__ WGU, F16* __restrict__ WD) {
  __shared__ F16 tl[64 * 258];   // 33 KB
  const int id = blockIdx.x, tid = threadIdx.x;
  int nt, kt, N, sel = 0;
  bool il;
  const float* src;
  F16* dchunk;   // base of the [n][64] chunk this block writes into
  if (id < NBWGU) {
    const int z = id >> 7, rem = id & 127;
    nt = rem & 7; kt = rem >> 3;           // N=2048: 8 nt; K=1024: 16 kt
    N = FF; il = true; sel = z & 1;
    const int e = z >> 1;
    src = sel ? ((e < NE) ? wup + (size_t)e * C * FF : su)
              : ((e < NE) ? wgate + (size_t)e * C * FF : sg);
    dchunk = WGU + (size_t)e * 2 * FF * C + (size_t)kt * (2 * FF * 64);
  } else {
    const int id2 = id - NBWGU;
    const int z = id2 >> 7, rem = id2 & 127;
    nt = rem & 3; kt = rem >> 2;           // N=1024: 4 nt; K=2048: 32 kt
    N = C; il = false;
    src = (z < NE) ? wdown + (size_t)z * FF * C : sd;
    dchunk = WD + (size_t)z * C * FF + (size_t)kt * (C * 64);
  }
  const int n0 = nt * 256, k0 = kt * 64;

  // load 64k x 256n fp32 tile: 16 float4 per thread, 1KB per wave-instr
#pragma unroll
  for (int u = 0; u < 16; ++u) {
    const int flat = u * 256 + tid;
    const int row = flat >> 6;             // k-local
    const int c4 = (flat & 63) * 4;        // n-local
    const float4 v = *(const float4*)&src[(size_t)(k0 + row) * N + n0 + c4];
    f16x4 h;
    h[0] = (F16)v.x; h[1] = (F16)v.y; h[2] = (F16)v.z; h[3] = (F16)v.w;
    *(f16x4*)&tl[row * 258 + c4] = h;
  }
  __syncthreads();

  // store: 8 f16x8 per thread; instr j: lanes cover 8 out-rows x 128B = 1KB
#pragma unroll
  for (int j = 0; j < 8; ++j) {
    const int flat = j * 256 + tid;
    const int nl = flat >> 3;              // n-local 0..255
    const int o = flat & 7;                // k-chunk
    f16x8 ov;
#pragma unroll
    for (int u = 0; u < 8; ++u) ov[u] = tl[(o * 8 + u) * 258 + nl];
    const int n = n0 + nl;
    const int row = il ? (((n >> 4) << 5) | (sel << 4) | (n & 15)) : n;
    *(f16x8*)&dchunk[(size_t)row * 64 + o * 8] = ov;
  }
}

// ======= router v2: conflict-free LDS, fp64 logits, top-2 ===================
// Lane owns float4 chunks i*64+lane: every LDS/global access is 16B
// lane-sequential (ds_read_b128 conflict-free, 1KB global bursts).
__global__ __launch_bounds__(256) void k_router(
    const float* __restrict__ x, const float* __restrict__ rw,
    F16* __restrict__ xh, int* __restrict__ meta,
    int* __restrict__ te0, int* __restrict__ te1,
    float* __restrict__ tw0, float* __restrict__ tw1) {
  __shared__ float4 lrw4[NE * C / 4];   // 32 KB
  const int tid = threadIdx.x;
  const float4* rw4 = (const float4*)rw;
#pragma unroll
  for (int j = 0; j < 8; ++j)
    lrw4[tid + j * 256] = rw4[tid + j * 256];
  __syncthreads();
  const int lane = tid & 63, wid = tid >> 6;
  const int tok = blockIdx.x * 4 + wid;
  const float4* xr4 = (const float4*)(x + (size_t)tok * C);
  float4 xv[4];
#pragma unroll
  for (int i = 0; i < 4; ++i) xv[i] = xr4[i * 64 + lane];
  // fused fp32 -> fp16 cast of x (512B contiguous per instr)
#pragma unroll
  for (int i = 0; i < 4; ++i) {
    f16x4 o;
    o[0] = (F16)xv[i].x; o[1] = (F16)xv[i].y;
    o[2] = (F16)xv[i].z; o[3] = (F16)xv[i].w;
    ((f16x4*)(xh + (size_t)tok * C))[i * 64 + lane] = o;
  }
  double lg[NE];
#pragma unroll
  for (int e = 0; e < NE; ++e) {
    double s = 0.0;
#pragma unroll
    for (int i = 0; i < 4; ++i) {
      const float4 w = lrw4[e * 256 + i * 64 + lane];
      s += (double)xv[i].x * (double)w.x + (double)xv[i].y * (double)w.y +
           (double)xv[i].z * (double)w.z + (double)xv[i].w * (double)w.w;
    }
    lg[e] = s;
  }
  // butterfly: 8 experts interleaved per step (ILP)
#pragma unroll
  for (int d = 1; d < 64; d <<= 1)
#pragma unroll
    for (int e = 0; e < NE; ++e) lg[e] += __shfl_xor(lg[e], d, 64);
  double b0 = -1e300; int i0 = 0;
#pragma unroll
  for (int e = 0; e < NE; ++e) if (lg[e] > b0) { b0 = lg[e]; i0 = e; }
  double b1 = -1e300; int i1 = 0;
#pragma unroll
  for (int e = 0; e < NE; ++e) if (e != i0 && lg[e] > b1) { b1 = lg[e]; i1 = e; }
  const float ex = __expf((float)(b1 - b0));
  const float w0 = 1.f / (1.f + ex), w1 = ex / (1.f + ex);
  if (lane == 0) {
    te0[tok] = i0; te1[tok] = i1; tw0[tok] = w0; tw1[tok] = w1;
    atomicAdd(&meta[MI_CNT + i0], 1);
    atomicAdd(&meta[MI_CNT + i1], 1);
  }
}

// ---------------- scan: bases, tile map (routed + shared), pad fill ----------
__global__ __launch_bounds__(256) void k_scan(int* __restrict__ meta,
                                              int* __restrict__ rowtok) {
  __shared__ int s_cnt[NE], s_base[NE];
  if (threadIdx.x == 0) {
    int b = 0, nt = 0;
    for (int e = 0; e < NE; e++) {
      int c = meta[MI_CNT + e];
      s_cnt[e] = c; s_base[e] = b;
      meta[MI_BASE + e] = b;
      meta[MI_CUR + e] = 0;
      int tiles = (c + 255) >> 8;
      for (int t = 0; t < tiles; t++) {
        meta[MI_TE + nt] = e;
        meta[MI_TR + nt] = b + t * 256;
        nt++;
      }
      b += tiles << 8;
    }
    for (int t = nt; t < NRT; t++) meta[MI_TE + t] = -1;
    for (int t = 0; t < NST; t++) {
      meta[MI_TE + NRT + t] = NE;
      meta[MI_TR + NRT + t] = SBASE + t * 256;
    }
  }
  __syncthreads();
  for (int e = 0; e < NE; e++) {
    int c = s_cnt[e], b = s_base[e];
    int al = (c + 255) & ~255;
    for (int i = c + threadIdx.x; i < al; i += 256) rowtok[b + i] = -1;
  }
}

// ---------------- scatter tokens into expert buckets (+slot record) ---------
__global__ __launch_bounds__(256) void k_scatter(const int* __restrict__ te0,
                                                 const int* __restrict__ te1,
                                                 int* __restrict__ meta,
                                                 int* __restrict__ rowtok,
                                                 int* __restrict__ sl0,
                                                 int* __restrict__ sl1) {
  int t = blockIdx.x * 256 + threadIdx.x;
  int e0 = te0[t], e1 = te1[t];
  int p0 = atomicAdd(&meta[MI_CUR + e0], 1);
  int r0 = meta[MI_BASE + e0] + p0;
  rowtok[r0] = t; sl0[t] = r0;
  int p1 = atomicAdd(&meta[MI_CUR + e1], 1);
  int r1 = meta[MI_BASE + e1] + p1;
  rowtok[r1] = t; sl1[t] = r1;
}

// ============ MFMA / ds_read helpers ============
__device__ __forceinline__ void read_a(f16x8 (&ar)[2][2], const F16* sAc,
                                       const int* aoff, int m0) {
  ar[0][0] = *(const f16x8*)&sAc[aoff[m0]];
  ar[0][1] = *(const f16x8*)&sAc[aoff[m0] ^ 32];
  ar[1][0] = *(const f16x8*)&sAc[aoff[m0 + 1]];
  ar[1][1] = *(const f16x8*)&sAc[aoff[m0 + 1] ^ 32];
}
__device__ __forceinline__ void mfma_pair(f32x4 (&a0)[4], f32x4 (&a1)[4],
                                          const f16x8 (&ar)[2][2],
                                          const f16x8 (&bb)[4][2]) {
#pragma unroll
  for (int ni = 0; ni < 4; ++ni) {
    a0[ni] = __builtin_amdgcn_mfma_f32_16x16x32_f16(ar[0][0], bb[ni][0], a0[ni], 0, 0, 0);
    a1[ni] = __builtin_amdgcn_mfma_f32_16x16x32_f16(ar[1][0], bb[ni][0], a1[ni], 0, 0, 0);
  }
#pragma unroll
  for (int ni = 0; ni < 4; ++ni) {
    a0[ni] = __builtin_amdgcn_mfma_f32_16x16x32_f16(ar[0][1], bb[ni][1], a0[ni], 0, 0, 0);
    a1[ni] = __builtin_amdgcn_mfma_f32_16x16x32_f16(ar[1][1], bb[ni][1], a1[ni], 0, 0, 0);
  }
}

// ======= unified 256x256 grouped GEMM — R14 frame + packed LDS epilogue =====
template <bool G1>
__global__ __launch_bounds__(512, 2) void k_gemm(const F16* __restrict__ Asrc,
                                                 const F16* __restrict__ Wsrc,
                                                 F16* __restrict__ Dst,
                                                 const int* __restrict__ meta,
                                                 const int* __restrict__ rowtok) {
  constexpr int K = G1 ? C : FF;
  constexpr int NT = K / 64;
  constexpr int TILE = 256 * 64;
  constexpr size_t BCH = (size_t)(G1 ? 2 * FF : C) * 64;   // B chunk stride
  const int e = meta[MI_TE + blockIdx.x];
  if (e < 0) return;
  const int row0 = meta[MI_TR + blockIdx.x];
  const int nb = blockIdx.y;
  const int n0 = nb * 256;
  const F16* WB = Wsrc + (size_t)e * (size_t)(G1 ? 2 * FF : C) * K;
  __shared__ __align__(16) F16 smem[4 * TILE];   // 128 KB: A0,A1,B0,B1
  const int tid = threadIdx.x, lane = tid & 63, wid = tid >> 6;
  const int wm = wid >> 2, wn = wid & 3;

  const int srow = tid >> 3;
  const int scol = ((tid & 7) ^ (srow & 7)) << 3;
  const F16 *pa0[4], *pb0[4];
#pragma unroll
  for (int i = 0; i < 4; ++i) {
    const int r = i * 64 + srow;
    int arow;
    if (G1) {
      int tok = (e == NE) ? (row0 - SBASE + r) : rowtok[row0 + r];
      if (tok < 0) tok = 0;   // pad row: harmless dup, never combined
      arow = tok;
    } else {
      arow = row0 + r;
    }
    pa0[i] = G1 ? (Asrc + (size_t)arow * C + scol)
                : (Asrc + (size_t)arow * 128 + scol);    // H tiled [ct][row][128]
    pb0[i] = WB + (size_t)(n0 + i * 64 + srow) * 64 + scol;  // chunk-tiled
  }
  const int ldsrow = wid * 8;
  auto a_off = [&](int t1) -> size_t {
    return G1 ? (size_t)t1 * 64
              : (size_t)(t1 >> 1) * ((size_t)ROWS * 128) + (size_t)(t1 & 1) * 64;
  };

  const int fro = lane & 15, q = lane >> 4;
  int aoff[8], boff[4];
#pragma unroll
  for (int f = 0; f < 8; ++f) {
    const int r = wm * 128 + f * 16 + fro;
    aoff[f] = r * 64 + ((q ^ (r & 7)) << 3);
  }
#pragma unroll
  for (int ni = 0; ni < 4; ++ni) {
    const int r = wn * 64 + ni * 16 + fro;
    boff[ni] = r * 64 + ((q ^ (r & 7)) << 3);
  }

  f32x4 acc[8][4];
  const f32x4 fz = {0.f, 0.f, 0.f, 0.f};
#pragma unroll
  for (int i = 0; i < 8; ++i)
#pragma unroll
    for (int j = 0; j < 4; ++j) acc[i][j] = fz;

  // prologue: stage tile 0 (A -> smem[0], B -> smem[2*TILE])
#pragma unroll
  for (int i = 0; i < 4; ++i) {
    gload16(pa0[i], &smem[(i * 64 + ldsrow) * 64]);
    gload16(pb0[i], &smem[2 * TILE + (i * 64 + ldsrow) * 64]);
  }

  for (int t = 0; t < NT; ++t) {
    const int cur = t & 1, nxt = cur ^ 1;
    const F16* sAc = smem + cur * TILE;
    const F16* sBc = smem + (2 + cur) * TILE;
    F16* sAn = smem + nxt * TILE;
    F16* sBn = smem + (2 + nxt) * TILE;
    const bool st = (t + 1 < NT);
    const size_t ag = a_off(t + 1);
    const size_t bg = (size_t)(t + 1) * BCH;

    if (st) {
#pragma unroll
      for (int i = 0; i < 4; ++i)
        gload16(pa0[i] + ag, &sAn[(i * 64 + ldsrow) * 64]);
      VMCNT4();
    } else {
      VMCNT0();
    }
    BARR();

    f16x8 bb[4][2], ar[2][2];
#pragma unroll
    for (int ni = 0; ni < 4; ++ni) {
      bb[ni][0] = *(const f16x8*)&sBc[boff[ni]];
      bb[ni][1] = *(const f16x8*)&sBc[boff[ni] ^ 32];
    }

    read_a(ar, sAc, aoff, 0);
    PRIO1(); mfma_pair(acc[0], acc[1], ar, bb); PRIO0();
    if (st) {
      gload16(pb0[0] + bg, &sBn[ldsrow * 64]);
      gload16(pb0[1] + bg, &sBn[(64 + ldsrow) * 64]);
    }
    read_a(ar, sAc, aoff, 2);
    PRIO1(); mfma_pair(acc[2], acc[3], ar, bb); PRIO0();
    if (st) {
      gload16(pb0[2] + bg, &sBn[(128 + ldsrow) * 64]);
      gload16(pb0[3] + bg, &sBn[(192 + ldsrow) * 64]);
    }
    read_a(ar, sAc, aoff, 4);
    PRIO1(); mfma_pair(acc[4], acc[5], ar, bb); PRIO0();
    read_a(ar, sAc, aoff, 6);
    PRIO1(); mfma_pair(acc[6], acc[7], ar, bb); PRIO0();

    if (st) BARR();
  }

  // ===== packed epilogue =====
  const int erow = q << 2, ecol = fro;
  BARR();   // all waves done reading smem K-tiles before overwrite
  if (G1) {
    F16* ep = smem;
#pragma unroll
    for (int mi = 0; mi < 8; ++mi)
#pragma unroll
      for (int pp = 0; pp < 2; ++pp)
#pragma unroll
        for (int j = 0; j < 4; ++j) {
          const int rl = wm * 128 + mi * 16 + erow + j;
          const float gv = acc[mi][2 * pp][j], uv = acc[mi][2 * pp + 1][j];
          const float h = gv / (1.f + __expf(-gv)) * uv;
          ep[rl * 136 + wn * 32 + pp * 16 + ecol] = (F16)h;
        }
    BARR();
    F16* Hc = Dst + (size_t)nb * ((size_t)ROWS * 128);
#pragma unroll
    for (int i = 0; i < 16; ++i) {
      const int flat = i * 512 + tid;
      const int row = flat >> 5, col4 = flat & 31;
      const f16x4 v = *(const f16x4*)&ep[row * 136 + col4 * 4];
      *(f16x4*)&Hc[(size_t)(row0 + row) * 128 + col4 * 4] = v;
    }
  } else {
    F16* ep = smem;
    F16* Yc = Dst + (size_t)nb * ((size_t)ROWS * 256);
#pragma unroll
    for (int h = 0; h < 2; ++h) {
      if (wm == h) {
#pragma unroll
        for (int mi = 0; mi < 8; ++mi)
#pragma unroll
          for (int ni = 0; ni < 4; ++ni)
#pragma unroll
            for (int j = 0; j < 4; ++j) {
              const int rl = mi * 16 + erow + j;
              ep[rl * 264 + wn * 64 + ni * 16 + ecol] = (F16)acc[mi][ni][j];
            }
      }
      BARR();
#pragma unroll
      for (int i = 0; i < 16; ++i) {
        const int flat = i * 512 + tid;
        const int row = flat >> 6, col4 = flat & 63;
        const f16x4 v = *(const f16x4*)&ep[row * 264 + col4 * 4];
        *(f16x4*)&Yc[(size_t)(row0 + h * 128 + row) * 256 + col4 * 4] = v;
      }
      if (h == 0) BARR();
    }
  }
}

// ---------------- combine: out = w0*Y[r0] + w1*Y[r1] + Y[shared] ------------
__global__ __launch_bounds__(256) void k_combine(const F16* __restrict__ Y,
                                                 const int* __restrict__ sl0,
                                                 const int* __restrict__ sl1,
                                                 const float* __restrict__ tw0,
                                                 const float* __restrict__ tw1,
                                                 float* __restrict__ out) {
  int idx = blockIdx.x * 256 + threadIdx.x;
  int t = idx >> 7, cg = idx & 127;
  int r0 = sl0[t], r1 = sl1[t];
  float w0 = tw0[t], w1 = tw1[t];
  const F16* Yc = Y + (size_t)(cg >> 5) * ((size_t)ROWS * 256);
  const int cin = (cg & 31) * 8;
  f16x8 y0 = *(const f16x8*)&Yc[(size_t)r0 * 256 + cin];
  f16x8 y1 = *(const f16x8*)&Yc[(size_t)r1 * 256 + cin];
  f16x8 ys = *(const f16x8*)&Yc[(size_t)(SBASE + t) * 256 + cin];
  float o[8];
#pragma unroll
  for (int j = 0; j < 8; j++)
    o[j] = w0 * (float)y0[j] + w1 * (float)y1[j] + (float)ys[j];
  float* op = out + (size_t)t * C + cg * 8;
  ((float4*)op)[0] = make_float4(o[0], o[1], o[2], o[3]);
  ((float4*)op)[1] = make_float4(o[4], o[5], o[6], o[7]);
}

// ---------------- host launch ----------------
extern "C" void kernel_launch(void* const* d_in, const int* in_sizes, int n_in,
                              void* d_out, int out_size, void* d_ws, size_t ws_size,
                              hipStream_t stream) {
  const float* x  = (const float*)d_in[0];
  const float* rw = (const float*)d_in[1];
  const float* wgate = (const float*)d_in[2];
  const float* wup   = (const float*)d_in[3];
  const float* wdown = (const float*)d_in[4];
  const float* sg = (const float*)d_in[5];
  const float* su = (const float*)d_in[6];
  const float* sd = (const float*)d_in[7];
  float* out = (float*)d_out;

  char* ws = (char*)d_ws;
  size_t o = 0;
  auto alloc = [&](size_t bytes) -> void* {
    void* p = ws + o;
    o += (bytes + 255) & ~(size_t)255;
    return p;
  };
  F16* xh  = (F16*)alloc((size_t)NTOK * C * 2);
  F16* WGU = (F16*)alloc((size_t)9 * 2 * FF * C * 2);
  F16* WD  = (F16*)alloc((size_t)9 * C * FF * 2);
  F16* Hb  = (F16*)alloc((size_t)ROWS * FF * 2);
  int* rowtok = (int*)alloc((size_t)SBASE * 4);
  int* meta = (int*)alloc(2048);
  int* te0 = (int*)alloc((size_t)NTOK * 4);
  int* te1 = (int*)alloc((size_t)NTOK * 4);
  float* tw0 = (float*)alloc((size_t)NTOK * 4);
  float* tw1 = (float*)alloc((size_t)NTOK * 4);
  int* sl0 = (int*)alloc((size_t)NTOK * 4);
  int* sl1 = (int*)alloc((size_t)NTOK * 4);
  if (o > ws_size) return;
  F16* Yb = WGU;   // overlay: WGU dead after gemm1; Y (54.5MB) < WGU (75.5MB)

  (void)hipMemsetAsync(meta, 0, 1024, stream);
  k_tw<<<NBWGU + NBWD, 256, 0, stream>>>(wgate, sg, wup, su, wdown, sd, WGU, WD);
  k_router<<<NBRT, 256, 0, stream>>>(x, rw, xh, meta, te0, te1, tw0, tw1);
  k_scan<<<1, 256, 0, stream>>>(meta, rowtok);
  k_scatter<<<NTOK / 256, 256, 0, stream>>>(te0, te1, meta, rowtok, sl0, sl1);
  k_gemm<true><<<dim3(MAXT, 2 * FF / 256), 512, 0, stream>>>(xh, WGU, Hb, meta, rowtok);
  k_gemm<false><<<dim3(MAXT, C / 256), 512, 0, stream>>>(Hb, WD, Yb, meta, rowtok);
  k_combine<<<NTOK * (C / 8) / 256, 256, 0, stream>>>(Yb, sl0, sl1, tw0, tw1, out);
}

// Round 17
// 539.218 us; speedup vs baseline: 1.3660x; 1.3012x over previous
//
#include <hip/hip_runtime.h>

typedef _Float16 F16;
typedef __attribute__((ext_vector_type(8))) _Float16 f16x8;
typedef __attribute__((ext_vector_type(4))) _Float16 f16x4;
typedef __attribute__((ext_vector_type(4))) float f32x4;

constexpr int NTOK = 8192;   // B*T
constexpr int C    = 1024;   // d_model
constexpr int FF   = 2048;   // d_ff
constexpr int NE   = 8;      // experts
constexpr int NRT  = 72;     // max routed 256-row tiles: 16384/256 + 8
constexpr int NST  = 32;     // shared-expert tiles: 8192/256
constexpr int MAXT = NRT + NST;     // 104
constexpr int SBASE = NRT * 256;    // shared rows start here in H/Y
constexpr int ROWS = SBASE + NTOK;  // 26624

constexpr int NBWGU = 18 * 128;     // gate/up: 16 kt * 8 nt per z
constexpr int NBWD  = 9 * 128;      // w_down: 32 kt * 4 nt per z
constexpr int NBRT  = NTOK / 4;     // router blocks

// ---- tiled layouts ----
// WGU: per e: [C/64 kt][2FF n'][64]   (n' = gate/up 16-col interleave)
// WD : per z: [FF/64 kt][C n][64]
// H  : [16 ct][ROWS][128]   (ct = ffcol/128)
// Y  : [4 ct][ROWS][256]    (ct = col/256)

#define MI_CNT 0
#define MI_CUR 8
#define MI_BASE 16
#define MI_TE 32
#define MI_TR (32 + MAXT)

__device__ __forceinline__ void gload16(const void* g, void* l) {
  __builtin_amdgcn_global_load_lds(
      (__attribute__((address_space(1))) void*)g,
      (__attribute__((address_space(3))) void*)l, 16, 0, 0);
}
#define VMCNT4() asm volatile("s_waitcnt vmcnt(4)" ::: "memory")
#define VMCNT0() asm volatile("s_waitcnt vmcnt(0)" ::: "memory")
#define BARR()   __builtin_amdgcn_s_barrier()
#define PRIO1()  __builtin_amdgcn_s_setprio(1)
#define PRIO0()  __builtin_amdgcn_s_setprio(0)

// ======= weight transpose+cast v3: all-coalesced via LDS bounce =============
__global__ __launch_bounds__(256) void k_tw(
    const float* __restrict__ wgate, const float* __restrict__ sg,
    const float* __restrict__ wup, const float* __restrict__ su,
    const float* __restrict__ wdown, const float* __restrict__ sd,
    F16* __restrict__ WGU, F16* __restrict__ WD) {
  __shared__ F16 tl[64 * 258];   // 33 KB
  const int id = blockIdx.x, tid = threadIdx.x;
  int nt, kt, N, sel = 0;
  bool il;
  const float* src;
  F16* dchunk;   // base of the [n][64] chunk this block writes into
  if (id < NBWGU) {
    const int z = id >> 7, rem = id & 127;
    nt = rem & 7; kt = rem >> 3;           // N=2048: 8 nt; K=1024: 16 kt
    N = FF; il = true; sel = z & 1;
    const int e = z >> 1;
    src = sel ? ((e < NE) ? wup + (size_t)e * C * FF : su)
              : ((e < NE) ? wgate + (size_t)e * C * FF : sg);
    dchunk = WGU + (size_t)e * 2 * FF * C + (size_t)kt * (2 * FF * 64);
  } else {
    const int id2 = id - NBWGU;
    const int z = id2 >> 7, rem = id2 & 127;
    nt = rem & 3; kt = rem >> 2;           // N=1024: 4 nt; K=2048: 32 kt
    N = C; il = false;
    src = (z < NE) ? wdown + (size_t)z * FF * C : sd;
    dchunk = WD + (size_t)z * C * FF + (size_t)kt * (C * 64);
  }
  const int n0 = nt * 256, k0 = kt * 64;

  // load 64k x 256n fp32 tile: 16 float4 per thread, 1KB per wave-instr
#pragma unroll
  for (int u = 0; u < 16; ++u) {
    const int flat = u * 256 + tid;
    const int row = flat >> 6;             // k-local
    const int c4 = (flat & 63) * 4;        // n-local
    const float4 v = *(const float4*)&src[(size_t)(k0 + row) * N + n0 + c4];
    f16x4 h;
    h[0] = (F16)v.x; h[1] = (F16)v.y; h[2] = (F16)v.z; h[3] = (F16)v.w;
    *(f16x4*)&tl[row * 258 + c4] = h;
  }
  __syncthreads();

  // store: 8 f16x8 per thread; instr j: lanes cover 8 out-rows x 128B = 1KB
#pragma unroll
  for (int j = 0; j < 8; ++j) {
    const int flat = j * 256 + tid;
    const int nl = flat >> 3;              // n-local 0..255
    const int o = flat & 7;                // k-chunk
    f16x8 ov;
#pragma unroll
    for (int u = 0; u < 8; ++u) ov[u] = tl[(o * 8 + u) * 258 + nl];
    const int n = n0 + nl;
    const int row = il ? (((n >> 4) << 5) | (sel << 4) | (n & 15)) : n;
    *(f16x8*)&dchunk[(size_t)row * 64 + o * 8] = ov;
  }
}

// ======= router v3: NO atomics (counting moved to k_scan) ===================
// Lane owns float4 chunks i*64+lane: conflict-free LDS, 1KB global bursts.
__global__ __launch_bounds__(256) void k_router(
    const float* __restrict__ x, const float* __restrict__ rw,
    F16* __restrict__ xh,
    int* __restrict__ te0, int* __restrict__ te1,
    float* __restrict__ tw0, float* __restrict__ tw1) {
  __shared__ float4 lrw4[NE * C / 4];   // 32 KB
  const int tid = threadIdx.x;
  const float4* rw4 = (const float4*)rw;
#pragma unroll
  for (int j = 0; j < 8; ++j)
    lrw4[tid + j * 256] = rw4[tid + j * 256];
  __syncthreads();
  const int lane = tid & 63, wid = tid >> 6;
  const int tok = blockIdx.x * 4 + wid;
  const float4* xr4 = (const float4*)(x + (size_t)tok * C);
  float4 xv[4];
#pragma unroll
  for (int i = 0; i < 4; ++i) xv[i] = xr4[i * 64 + lane];
  // fused fp32 -> fp16 cast of x (512B contiguous per instr)
#pragma unroll
  for (int i = 0; i < 4; ++i) {
    f16x4 o;
    o[0] = (F16)xv[i].x; o[1] = (F16)xv[i].y;
    o[2] = (F16)xv[i].z; o[3] = (F16)xv[i].w;
    ((f16x4*)(xh + (size_t)tok * C))[i * 64 + lane] = o;
  }
  double lg[NE];
#pragma unroll
  for (int e = 0; e < NE; ++e) {
    double s = 0.0;
#pragma unroll
    for (int i = 0; i < 4; ++i) {
      const float4 w = lrw4[e * 256 + i * 64 + lane];
      s += (double)xv[i].x * (double)w.x + (double)xv[i].y * (double)w.y +
           (double)xv[i].z * (double)w.z + (double)xv[i].w * (double)w.w;
    }
    lg[e] = s;
  }
#pragma unroll
  for (int d = 1; d < 64; d <<= 1)
#pragma unroll
    for (int e = 0; e < NE; ++e) lg[e] += __shfl_xor(lg[e], d, 64);
  double b0 = -1e300; int i0 = 0;
#pragma unroll
  for (int e = 0; e < NE; ++e) if (lg[e] > b0) { b0 = lg[e]; i0 = e; }
  double b1 = -1e300; int i1 = 0;
#pragma unroll
  for (int e = 0; e < NE; ++e) if (e != i0 && lg[e] > b1) { b1 = lg[e]; i1 = e; }
  const float ex = __expf((float)(b1 - b0));
  const float w0 = 1.f / (1.f + ex), w1 = ex / (1.f + ex);
  if (lane == 0) {
    te0[tok] = i0; te1[tok] = i1; tw0[tok] = w0; tw1[tok] = w1;
  }
}

// ------- scan: parallel histogram + bases + tile map + pad fill -------------
__global__ __launch_bounds__(256) void k_scan(const int* __restrict__ te0,
                                              const int* __restrict__ te1,
                                              int* __restrict__ meta,
                                              int* __restrict__ rowtok) {
  __shared__ int hist[NE * 256];   // 8 KB
  __shared__ int s_cnt[NE], s_base[NE];
  const int tid = threadIdx.x;
  // private counters, statically indexed (rule #20)
  int c[NE] = {0, 0, 0, 0, 0, 0, 0, 0};
  for (int i = tid; i < NTOK; i += 256) {
    const int e0 = te0[i], e1 = te1[i];
#pragma unroll
    for (int e = 0; e < NE; ++e) c[e] += (e0 == e) + (e1 == e);
  }
#pragma unroll
  for (int e = 0; e < NE; ++e) hist[e * 256 + tid] = c[e];
  __syncthreads();
  for (int s = 128; s > 0; s >>= 1) {
    if (tid < s) {
#pragma unroll
      for (int e = 0; e < NE; ++e)
        hist[e * 256 + tid] += hist[e * 256 + tid + s];
    }
    __syncthreads();
  }
  if (tid == 0) {
    int b = 0, nt = 0;
    for (int e = 0; e < NE; e++) {
      int cc = hist[e * 256];
      s_cnt[e] = cc; s_base[e] = b;
      meta[MI_BASE + e] = b;
      meta[MI_CUR + e] = 0;
      int tiles = (cc + 255) >> 8;
      for (int t = 0; t < tiles; t++) {
        meta[MI_TE + nt] = e;
        meta[MI_TR + nt] = b + t * 256;
        nt++;
      }
      b += tiles << 8;
    }
    for (int t = nt; t < NRT; t++) meta[MI_TE + t] = -1;
    for (int t = 0; t < NST; t++) {
      meta[MI_TE + NRT + t] = NE;
      meta[MI_TR + NRT + t] = SBASE + t * 256;
    }
  }
  __syncthreads();
  for (int e = 0; e < NE; e++) {
    int cc = s_cnt[e], b = s_base[e];
    int al = (cc + 255) & ~255;
    for (int i = cc + tid; i < al; i += 256) rowtok[b + i] = -1;
  }
}

// ---------------- scatter tokens into expert buckets (+slot record) ---------
__global__ __launch_bounds__(256) void k_scatter(const int* __restrict__ te0,
                                                 const int* __restrict__ te1,
                                                 int* __restrict__ meta,
                                                 int* __restrict__ rowtok,
                                                 int* __restrict__ sl0,
                                                 int* __restrict__ sl1) {
  int t = blockIdx.x * 256 + threadIdx.x;
  int e0 = te0[t], e1 = te1[t];
  int p0 = atomicAdd(&meta[MI_CUR + e0], 1);
  int r0 = meta[MI_BASE + e0] + p0;
  rowtok[r0] = t; sl0[t] = r0;
  int p1 = atomicAdd(&meta[MI_CUR + e1], 1);
  int r1 = meta[MI_BASE + e1] + p1;
  rowtok[r1] = t; sl1[t] = r1;
}

// ============ MFMA / ds_read helpers ============
__device__ __forceinline__ void read_a(f16x8 (&ar)[2][2], const F16* sAc,
                                       const int* aoff, int m0) {
  ar[0][0] = *(const f16x8*)&sAc[aoff[m0]];
  ar[0][1] = *(const f16x8*)&sAc[aoff[m0] ^ 32];
  ar[1][0] = *(const f16x8*)&sAc[aoff[m0 + 1]];
  ar[1][1] = *(const f16x8*)&sAc[aoff[m0 + 1] ^ 32];
}
__device__ __forceinline__ void mfma_pair(f32x4 (&a0)[4], f32x4 (&a1)[4],
                                          const f16x8 (&ar)[2][2],
                                          const f16x8 (&bb)[4][2]) {
#pragma unroll
  for (int ni = 0; ni < 4; ++ni) {
    a0[ni] = __builtin_amdgcn_mfma_f32_16x16x32_f16(ar[0][0], bb[ni][0], a0[ni], 0, 0, 0);
    a1[ni] = __builtin_amdgcn_mfma_f32_16x16x32_f16(ar[1][0], bb[ni][0], a1[ni], 0, 0, 0);
  }
#pragma unroll
  for (int ni = 0; ni < 4; ++ni) {
    a0[ni] = __builtin_amdgcn_mfma_f32_16x16x32_f16(ar[0][1], bb[ni][1], a0[ni], 0, 0, 0);
    a1[ni] = __builtin_amdgcn_mfma_f32_16x16x32_f16(ar[1][1], bb[ni][1], a1[ni], 0, 0, 0);
  }
}

// ======= unified 256x256 grouped GEMM — R14 frame + packed LDS epilogue =====
template <bool G1>
__global__ __launch_bounds__(512, 2) void k_gemm(const F16* __restrict__ Asrc,
                                                 const F16* __restrict__ Wsrc,
                                                 F16* __restrict__ Dst,
                                                 const int* __restrict__ meta,
                                                 const int* __restrict__ rowtok) {
  constexpr int K = G1 ? C : FF;
  constexpr int NT = K / 64;
  constexpr int TILE = 256 * 64;
  constexpr size_t BCH = (size_t)(G1 ? 2 * FF : C) * 64;   // B chunk stride
  const int e = meta[MI_TE + blockIdx.x];
  if (e < 0) return;
  const int row0 = meta[MI_TR + blockIdx.x];
  const int nb = blockIdx.y;
  const int n0 = nb * 256;
  const F16* WB = Wsrc + (size_t)e * (size_t)(G1 ? 2 * FF : C) * K;
  __shared__ __align__(16) F16 smem[4 * TILE];   // 128 KB: A0,A1,B0,B1
  const int tid = threadIdx.x, lane = tid & 63, wid = tid >> 6;
  const int wm = wid >> 2, wn = wid & 3;

  const int srow = tid >> 3;
  const int scol = ((tid & 7) ^ (srow & 7)) << 3;
  const F16 *pa0[4], *pb0[4];
#pragma unroll
  for (int i = 0; i < 4; ++i) {
    const int r = i * 64 + srow;
    int arow;
    if (G1) {
      int tok = (e == NE) ? (row0 - SBASE + r) : rowtok[row0 + r];
      if (tok < 0) tok = 0;   // pad row: harmless dup, never combined
      arow = tok;
    } else {
      arow = row0 + r;
    }
    pa0[i] = G1 ? (Asrc + (size_t)arow * C + scol)
                : (Asrc + (size_t)arow * 128 + scol);    // H tiled [ct][row][128]
    pb0[i] = WB + (size_t)(n0 + i * 64 + srow) * 64 + scol;  // chunk-tiled
  }
  const int ldsrow = wid * 8;
  auto a_off = [&](int t1) -> size_t {
    return G1 ? (size_t)t1 * 64
              : (size_t)(t1 >> 1) * ((size_t)ROWS * 128) + (size_t)(t1 & 1) * 64;
  };

  const int fro = lane & 15, q = lane >> 4;
  int aoff[8], boff[4];
#pragma unroll
  for (int f = 0; f < 8; ++f) {
    const int r = wm * 128 + f * 16 + fro;
    aoff[f] = r * 64 + ((q ^ (r & 7)) << 3);
  }
#pragma unroll
  for (int ni = 0; ni < 4; ++ni) {
    const int r = wn * 64 + ni * 16 + fro;
    boff[ni] = r * 64 + ((q ^ (r & 7)) << 3);
  }

  f32x4 acc[8][4];
  const f32x4 fz = {0.f, 0.f, 0.f, 0.f};
#pragma unroll
  for (int i = 0; i < 8; ++i)
#pragma unroll
    for (int j = 0; j < 4; ++j) acc[i][j] = fz;

  // prologue: stage tile 0 (A -> smem[0], B -> smem[2*TILE])
#pragma unroll
  for (int i = 0; i < 4; ++i) {
    gload16(pa0[i], &smem[(i * 64 + ldsrow) * 64]);
    gload16(pb0[i], &smem[2 * TILE + (i * 64 + ldsrow) * 64]);
  }

  for (int t = 0; t < NT; ++t) {
    const int cur = t & 1, nxt = cur ^ 1;
    const F16* sAc = smem + cur * TILE;
    const F16* sBc = smem + (2 + cur) * TILE;
    F16* sAn = smem + nxt * TILE;
    F16* sBn = smem + (2 + nxt) * TILE;
    const bool st = (t + 1 < NT);
    const size_t ag = a_off(t + 1);
    const size_t bg = (size_t)(t + 1) * BCH;

    if (st) {
#pragma unroll
      for (int i = 0; i < 4; ++i)
        gload16(pa0[i] + ag, &sAn[(i * 64 + ldsrow) * 64]);
      VMCNT4();
    } else {
      VMCNT0();
    }
    BARR();

    f16x8 bb[4][2], ar[2][2];
#pragma unroll
    for (int ni = 0; ni < 4; ++ni) {
      bb[ni][0] = *(const f16x8*)&sBc[boff[ni]];
      bb[ni][1] = *(const f16x8*)&sBc[boff[ni] ^ 32];
    }

    read_a(ar, sAc, aoff, 0);
    PRIO1(); mfma_pair(acc[0], acc[1], ar, bb); PRIO0();
    if (st) {
      gload16(pb0[0] + bg, &sBn[ldsrow * 64]);
      gload16(pb0[1] + bg, &sBn[(64 + ldsrow) * 64]);
    }
    read_a(ar, sAc, aoff, 2);
    PRIO1(); mfma_pair(acc[2], acc[3], ar, bb); PRIO0();
    if (st) {
      gload16(pb0[2] + bg, &sBn[(128 + ldsrow) * 64]);
      gload16(pb0[3] + bg, &sBn[(192 + ldsrow) * 64]);
    }
    read_a(ar, sAc, aoff, 4);
    PRIO1(); mfma_pair(acc[4], acc[5], ar, bb); PRIO0();
    read_a(ar, sAc, aoff, 6);
    PRIO1(); mfma_pair(acc[6], acc[7], ar, bb); PRIO0();

    if (st) BARR();
  }

  // ===== packed epilogue =====
  const int erow = q << 2, ecol = fro;
  BARR();   // all waves done reading smem K-tiles before overwrite
  if (G1) {
    F16* ep = smem;
#pragma unroll
    for (int mi = 0; mi < 8; ++mi)
#pragma unroll
      for (int pp = 0; pp < 2; ++pp)
#pragma unroll
        for (int j = 0; j < 4; ++j) {
          const int rl = wm * 128 + mi * 16 + erow + j;
          const float gv = acc[mi][2 * pp][j], uv = acc[mi][2 * pp + 1][j];
          const float h = gv / (1.f + __expf(-gv)) * uv;
          ep[rl * 136 + wn * 32 + pp * 16 + ecol] = (F16)h;
        }
    BARR();
    F16* Hc = Dst + (size_t)nb * ((size_t)ROWS * 128);
#pragma unroll
    for (int i = 0; i < 16; ++i) {
      const int flat = i * 512 + tid;
      const int row = flat >> 5, col4 = flat & 31;
      const f16x4 v = *(const f16x4*)&ep[row * 136 + col4 * 4];
      *(f16x4*)&Hc[(size_t)(row0 + row) * 128 + col4 * 4] = v;
    }
  } else {
    F16* ep = smem;
    F16* Yc = Dst + (size_t)nb * ((size_t)ROWS * 256);
#pragma unroll
    for (int h = 0; h < 2; ++h) {
      if (wm == h) {
#pragma unroll
        for (int mi = 0; mi < 8; ++mi)
#pragma unroll
          for (int ni = 0; ni < 4; ++ni)
#pragma unroll
            for (int j = 0; j < 4; ++j) {
              const int rl = mi * 16 + erow + j;
              ep[rl * 264 + wn * 64 + ni * 16 + ecol] = (F16)acc[mi][ni][j];
            }
      }
      BARR();
#pragma unroll
      for (int i = 0; i < 16; ++i) {
        const int flat = i * 512 + tid;
        const int row = flat >> 6, col4 = flat & 63;
        const f16x4 v = *(const f16x4*)&ep[row * 264 + col4 * 4];
        *(f16x4*)&Yc[(size_t)(row0 + h * 128 + row) * 256 + col4 * 4] = v;
      }
      if (h == 0) BARR();
    }
  }
}

// ---------------- combine: out = w0*Y[r0] + w1*Y[r1] + Y[shared] ------------
__global__ __launch_bounds__(256) void k_combine(const F16* __restrict__ Y,
                                                 const int* __restrict__ sl0,
                                                 const int* __restrict__ sl1,
                                                 const float* __restrict__ tw0,
                                                 const float* __restrict__ tw1,
                                                 float* __restrict__ out) {
  int idx = blockIdx.x * 256 + threadIdx.x;
  int t = idx >> 7, cg = idx & 127;
  int r0 = sl0[t], r1 = sl1[t];
  float w0 = tw0[t], w1 = tw1[t];
  const F16* Yc = Y + (size_t)(cg >> 5) * ((size_t)ROWS * 256);
  const int cin = (cg & 31) * 8;
  f16x8 y0 = *(const f16x8*)&Yc[(size_t)r0 * 256 + cin];
  f16x8 y1 = *(const f16x8*)&Yc[(size_t)r1 * 256 + cin];
  f16x8 ys = *(const f16x8*)&Yc[(size_t)(SBASE + t) * 256 + cin];
  float o[8];
#pragma unroll
  for (int j = 0; j < 8; j++)
    o[j] = w0 * (float)y0[j] + w1 * (float)y1[j] + (float)ys[j];
  float* op = out + (size_t)t * C + cg * 8;
  ((float4*)op)[0] = make_float4(o[0], o[1], o[2], o[3]);
  ((float4*)op)[1] = make_float4(o[4], o[5], o[6], o[7]);
}

// ---------------- host launch ----------------
extern "C" void kernel_launch(void* const* d_in, const int* in_sizes, int n_in,
                              void* d_out, int out_size, void* d_ws, size_t ws_size,
                              hipStream_t stream) {
  const float* x  = (const float*)d_in[0];
  const float* rw = (const float*)d_in[1];
  const float* wgate = (const float*)d_in[2];
  const float* wup   = (const float*)d_in[3];
  const float* wdown = (const float*)d_in[4];
  const float* sg = (const float*)d_in[5];
  const float* su = (const float*)d_in[6];
  const float* sd = (const float*)d_in[7];
  float* out = (float*)d_out;

  char* ws = (char*)d_ws;
  size_t o = 0;
  auto alloc = [&](size_t bytes) -> void* {
    void* p = ws + o;
    o += (bytes + 255) & ~(size_t)255;
    return p;
  };
  F16* xh  = (F16*)alloc((size_t)NTOK * C * 2);
  F16* WGU = (F16*)alloc((size_t)9 * 2 * FF * C * 2);
  F16* WD  = (F16*)alloc((size_t)9 * C * FF * 2);
  F16* Hb  = (F16*)alloc((size_t)ROWS * FF * 2);
  int* rowtok = (int*)alloc((size_t)SBASE * 4);
  int* meta = (int*)alloc(2048);
  int* te0 = (int*)alloc((size_t)NTOK * 4);
  int* te1 = (int*)alloc((size_t)NTOK * 4);
  float* tw0 = (float*)alloc((size_t)NTOK * 4);
  float* tw1 = (float*)alloc((size_t)NTOK * 4);
  int* sl0 = (int*)alloc((size_t)NTOK * 4);
  int* sl1 = (int*)alloc((size_t)NTOK * 4);
  if (o > ws_size) return;
  F16* Yb = WGU;   // overlay: WGU dead after gemm1; Y (54.5MB) < WGU (75.5MB)

  (void)hipMemsetAsync(meta, 0, 1024, stream);
  k_tw<<<NBWGU + NBWD, 256, 0, stream>>>(wgate, sg, wup, su, wdown, sd, WGU, WD);
  k_router<<<NBRT, 256, 0, stream>>>(x, rw, xh, te0, te1, tw0, tw1);
  k_scan<<<1, 256, 0, stream>>>(te0, te1, meta, rowtok);
  k_scatter<<<NTOK / 256, 256, 0, stream>>>(te0, te1, meta, rowtok, sl0, sl1);
  k_gemm<true><<<dim3(MAXT, 2 * FF / 256), 512, 0, stream>>>(xh, WGU, Hb, meta, rowtok);
  k_gemm<false><<<dim3(MAXT, C / 256), 512, 0, stream>>>(Hb, WD, Yb, meta, rowtok);
  k_combine<<<NTOK * (C / 8) / 256, 256, 0, stream>>>(Yb, sl0, sl1, tw0, tw1, out);
}